// Round 1
// baseline (216.776 us; speedup 1.0000x reference)
//
#include <hip/hip_runtime.h>
#include <math.h>

#define T_IN        480000
#define OUT_PER_ROW 432000
#define K_TOT       48000     // output 9-groups per row
#define GPB         256       // k-groups per block (1 per thread)
#define LDS_FLOATS  2576      // staged input span (10*255 + 23 + align slack)

struct ResampleW { float w[9][14]; };

__global__ __launch_bounds__(256)
void SpeedPerturb_resample_kernel(const float* __restrict__ in,
                                  float* __restrict__ out,
                                  ResampleW args)
{
    __shared__ float lds[LDS_FLOATS];
    const int row = blockIdx.y;
    const int k0  = blockIdx.x * GPB;
    const int t   = threadIdx.x;
    const int is0 = 10 * k0 - 6;     // first needed input index (fi[0] = -6)
    const int al  = is0 & ~3;        // floor to 16B-aligned float index
    const int off = is0 - al;        // 0 or 2
    const float* rin = in + (size_t)row * T_IN;

    // Stage [al, al + LDS_FLOATS) of this row into LDS, zero-filled out of range.
    for (int q = t; q < LDS_FLOATS / 4; q += 256) {
        const int g0 = al + 4 * q;
        float4 v;
        if (g0 >= 0 && g0 + 3 < T_IN) {
            v = *reinterpret_cast<const float4*>(rin + g0);
        } else {
            v.x = (g0 + 0 >= 0 && g0 + 0 < T_IN) ? rin[g0 + 0] : 0.f;
            v.y = (g0 + 1 >= 0 && g0 + 1 < T_IN) ? rin[g0 + 1] : 0.f;
            v.z = (g0 + 2 >= 0 && g0 + 2 < T_IN) ? rin[g0 + 2] : 0.f;
            v.w = (g0 + 3 >= 0 && g0 + 3 < T_IN) ? rin[g0 + 3] : 0.f;
        }
        *reinterpret_cast<float4*>(&lds[4 * q]) = v;
    }
    __syncthreads();

    const int k = k0 + t;
    if (k >= K_TOT) return;

    // 23-float input window for this k-group: input[10*k - 6 .. 10*k + 16]
    float v[23];
    const int base = off + 10 * t;
    #pragma unroll
    for (int m = 0; m < 23; ++m) v[m] = lds[base + m];

    // RB[i] = fi[i] + 6, fi = ceil(i*10/9 - 6.7340067) = {-6..-1,0,2,3}
    constexpr int RB[9] = {0, 1, 2, 3, 4, 5, 6, 8, 9};

    float* orow = out + (size_t)row * OUT_PER_ROW + 9 * (size_t)k;
    #pragma unroll
    for (int i = 0; i < 9; ++i) {
        float s = 0.f;
        #pragma unroll
        for (int j = 0; j < 14; ++j)
            s = fmaf(args.w[i][j], v[RB[i] + j], s);
        orow[i] = s;
    }
}

extern "C" void kernel_launch(void* const* d_in, const int* in_sizes, int n_in,
                              void* d_out, int out_size, void* d_ws, size_t ws_size,
                              hipStream_t stream) {
    const float* in  = (const float*)d_in[0];
    float*       out = (float*)d_out;
    const int B = out_size / OUT_PER_ROW;

    // Kaldi LinearResample weights, float64 math mirroring the reference.
    ResampleW args;
    const double orig = 16000.0;
    const double lowpass_cutoff = 0.99 * 0.5 * 14400.0;     // min_freq = 14400
    const double window_width = 6.0 / (2.0 * lowpass_cutoff);
    const double PI = 3.14159265358979323846;
    for (int i = 0; i < 9; ++i) {
        const double output_t = (double)i / 14400.0;
        const double min_input_index = ceil((output_t - window_width) * orig);
        for (int j = 0; j < 14; ++j) {
            const double delta_t = (min_input_index + j) / orig - output_t;
            double w = 0.0;
            if (fabs(delta_t) < window_width) {
                w = 0.5 * (1.0 + cos(2.0 * PI * lowpass_cutoff / 6.0 * delta_t));
                if (delta_t != 0.0)
                    w *= sin(2.0 * PI * lowpass_cutoff * delta_t) / (PI * delta_t);
                else
                    w *= 2.0 * lowpass_cutoff;
                w /= orig;
            }
            args.w[i][j] = (float)w;
        }
    }

    dim3 grid((K_TOT + GPB - 1) / GPB, B);
    SpeedPerturb_resample_kernel<<<grid, dim3(256), 0, stream>>>(in, out, args);
}

// Round 2
// 210.838 us; speedup vs baseline: 1.0282x; 1.0282x over previous
//
#include <hip/hip_runtime.h>
#include <math.h>

#define T_IN        480000
#define OUT_PER_ROW 432000
#define K_TOT       48000     // output 9-groups per row
#define GPB         256       // k-groups per block (1 per thread)
#define LDS_FLOATS  2576      // staged input span (10*255 + 23 + align slack)
#define OUT_LDS     (GPB * 9) // 2304 staged outputs per block

struct ResampleW { float w[9][14]; };

__global__ __launch_bounds__(256)
void SpeedPerturb_resample_kernel(const float* __restrict__ in,
                                  float* __restrict__ out,
                                  ResampleW args)
{
    __shared__ float lin[LDS_FLOATS];
    __shared__ float lout[OUT_LDS];
    const int row = blockIdx.y;
    const int k0  = blockIdx.x * GPB;
    const int t   = threadIdx.x;
    const int is0 = 10 * k0 - 6;     // first needed input index (fi[0] = -6)
    const int al  = is0 & ~3;        // floor to 16B-aligned float index
    const int off = is0 - al;        // 0 or 2 (always even)
    const float* rin = in + (size_t)row * T_IN;

    // Stage [al, al + LDS_FLOATS) of this row into LDS, zero-filled out of range.
    for (int q = t; q < LDS_FLOATS / 4; q += 256) {
        const int g0 = al + 4 * q;
        float4 v;
        if (g0 >= 0 && g0 + 3 < T_IN) {
            v = *reinterpret_cast<const float4*>(rin + g0);
        } else {
            v.x = (g0 + 0 >= 0 && g0 + 0 < T_IN) ? rin[g0 + 0] : 0.f;
            v.y = (g0 + 1 >= 0 && g0 + 1 < T_IN) ? rin[g0 + 1] : 0.f;
            v.z = (g0 + 2 >= 0 && g0 + 2 < T_IN) ? rin[g0 + 2] : 0.f;
            v.w = (g0 + 3 >= 0 && g0 + 3 < T_IN) ? rin[g0 + 3] : 0.f;
        }
        *reinterpret_cast<float4*>(&lin[4 * q]) = v;
    }
    __syncthreads();

    const int k = k0 + t;
    if (k < K_TOT) {
        // 23-float input window for this k-group: input[10*k - 6 .. 10*k + 16]
        // base = off + 10*t is even -> 8B-aligned -> ds_read_b64 pairs.
        float v[24];
        const int base = off + 10 * t;
        #pragma unroll
        for (int m = 0; m < 12; ++m) {
            float2 p = *reinterpret_cast<const float2*>(&lin[base + 2 * m]);
            v[2 * m]     = p.x;
            v[2 * m + 1] = p.y;
        }

        // RB[i] = fi[i] + 6, fi = ceil(i*10/9 - 6.7340067) = {-6..-1,0,2,3}
        constexpr int RB[9] = {0, 1, 2, 3, 4, 5, 6, 8, 9};

        #pragma unroll
        for (int i = 0; i < 9; ++i) {
            float s = 0.f;
            #pragma unroll
            for (int j = 0; j < 14; ++j)
                s = fmaf(args.w[i][j], v[RB[i] + j], s);
            lout[9 * t + i] = s;   // bank = (9t+i)%32, gcd(9,32)=1 -> 2 lanes/bank, free
        }
    }
    __syncthreads();

    // Coalesced float4 store of the block's contiguous output region.
    const int nout = min(OUT_LDS, (K_TOT - k0) * 9);   // 2304 or 1152, both %4==0
    float* obase = out + (size_t)row * OUT_PER_ROW + (size_t)k0 * 9;
    for (int q = t; q < nout / 4; q += 256) {
        *reinterpret_cast<float4*>(obase + 4 * q) =
            *reinterpret_cast<const float4*>(&lout[4 * q]);
    }
}

extern "C" void kernel_launch(void* const* d_in, const int* in_sizes, int n_in,
                              void* d_out, int out_size, void* d_ws, size_t ws_size,
                              hipStream_t stream) {
    const float* in  = (const float*)d_in[0];
    float*       out = (float*)d_out;
    const int B = out_size / OUT_PER_ROW;

    // Kaldi LinearResample weights, float64 math mirroring the reference.
    ResampleW args;
    const double orig = 16000.0;
    const double lowpass_cutoff = 0.99 * 0.5 * 14400.0;     // min_freq = 14400
    const double window_width = 6.0 / (2.0 * lowpass_cutoff);
    const double PI = 3.14159265358979323846;
    for (int i = 0; i < 9; ++i) {
        const double output_t = (double)i / 14400.0;
        const double min_input_index = ceil((output_t - window_width) * orig);
        for (int j = 0; j < 14; ++j) {
            const double delta_t = (min_input_index + j) / orig - output_t;
            double w = 0.0;
            if (fabs(delta_t) < window_width) {
                w = 0.5 * (1.0 + cos(2.0 * PI * lowpass_cutoff / 6.0 * delta_t));
                if (delta_t != 0.0)
                    w *= sin(2.0 * PI * lowpass_cutoff * delta_t) / (PI * delta_t);
                else
                    w *= 2.0 * lowpass_cutoff;
                w /= orig;
            }
            args.w[i][j] = (float)w;
        }
    }

    dim3 grid((K_TOT + GPB - 1) / GPB, B);
    SpeedPerturb_resample_kernel<<<grid, dim3(256), 0, stream>>>(in, out, args);
}

// Round 4
// 210.478 us; speedup vs baseline: 1.0299x; 1.0017x over previous
//
#include <hip/hip_runtime.h>
#include <math.h>

#define T_IN        480000
#define OUT_PER_ROW 432000
#define K_TOT       48000      // output 9-groups per row
#define PAIRS_PB    256        // one k-pair (2 groups) per thread
#define GROUPS_PB   (2 * PAIRS_PB)          // 512 k-groups per block
#define OUT_LDS     (GROUPS_PB * 9)         // 4608 staged outputs per block

struct ResampleW { float w[9][14]; };

__global__ __launch_bounds__(256)
void SpeedPerturb_resample_kernel(const float* __restrict__ in,
                                  float* __restrict__ out,
                                  ResampleW args)
{
    __shared__ float lout[OUT_LDS];
    const int row = blockIdx.y;
    const int k0  = blockIdx.x * GROUPS_PB;       // first k-group of block
    const int t   = threadIdx.x;
    const int kp  = (k0 >> 1) + t;                // global k-pair index
    const float* rin = in + (size_t)row * T_IN;

    // Window for pair kp: input[20*kp-6 .. 20*kp+26]; aligned base 20*kp-8
    // (20*kp % 4 == 0, so the float4 base is always 16B-aligned, offset 2).
    const int al = 20 * kp - 8;
    float v[36];
    const bool interior = (blockIdx.x > 0) && (blockIdx.x < gridDim.x - 1);
    if (interior) {
        // 9 independent dwordx4 loads, issued back-to-back: 9 KB/wave in flight.
        #pragma unroll
        for (int m = 0; m < 9; ++m) {
            float4 q = *reinterpret_cast<const float4*>(rin + al + 4 * m);
            v[4 * m + 0] = q.x; v[4 * m + 1] = q.y;
            v[4 * m + 2] = q.z; v[4 * m + 3] = q.w;
        }
    } else {
        #pragma unroll
        for (int m = 0; m < 36; ++m) {
            const int idx = al + m;
            v[m] = (idx >= 0 && idx < T_IN) ? rin[idx] : 0.f;
        }
    }

    // RB[i] = fi[i] + 6, fi = ceil(i*10/9 - 6.7340067) = {-6..-1,0,2,3}
    constexpr int RB[9] = {0, 1, 2, 3, 4, 5, 6, 8, 9};

    #pragma unroll
    for (int g = 0; g < 2; ++g) {
        const int k = k0 + 2 * t + g;
        if (k < K_TOT) {
            #pragma unroll
            for (int i = 0; i < 9; ++i) {
                float s = 0.f;
                #pragma unroll
                for (int j = 0; j < 14; ++j)
                    s = fmaf(args.w[i][j], v[2 + 10 * g + RB[i] + j], s);
                lout[18 * t + 9 * g + i] = s;
            }
        }
    }
    __syncthreads();

    // Coalesced float4 store of the block's contiguous output region.
    const int nout = min(OUT_LDS, (K_TOT - k0) * 9);   // 4608 or 3456, both %4==0
    float* obase = out + (size_t)row * OUT_PER_ROW + (size_t)k0 * 9;
    for (int q = t; q < (nout >> 2); q += 256) {
        *reinterpret_cast<float4*>(obase + 4 * q) =
            *reinterpret_cast<const float4*>(&lout[4 * q]);
    }
}

extern "C" void kernel_launch(void* const* d_in, const int* in_sizes, int n_in,
                              void* d_out, int out_size, void* d_ws, size_t ws_size,
                              hipStream_t stream) {
    const float* in  = (const float*)d_in[0];
    float*       out = (float*)d_out;
    const int B = out_size / OUT_PER_ROW;

    // Kaldi LinearResample weights, float64 math mirroring the reference.
    ResampleW args;
    const double orig = 16000.0;
    const double lowpass_cutoff = 0.99 * 0.5 * 14400.0;     // min_freq = 14400
    const double window_width = 6.0 / (2.0 * lowpass_cutoff);
    const double PI = 3.14159265358979323846;
    for (int i = 0; i < 9; ++i) {
        const double output_t = (double)i / 14400.0;
        const double min_input_index = ceil((output_t - window_width) * orig);
        for (int j = 0; j < 14; ++j) {
            const double delta_t = (min_input_index + j) / orig - output_t;
            double w = 0.0;
            if (fabs(delta_t) < window_width) {
                w = 0.5 * (1.0 + cos(2.0 * PI * lowpass_cutoff / 6.0 * delta_t));
                if (delta_t != 0.0)
                    w *= sin(2.0 * PI * lowpass_cutoff * delta_t) / (PI * delta_t);
                else
                    w *= 2.0 * lowpass_cutoff;
                w /= orig;
            }
            args.w[i][j] = (float)w;
        }
    }

    dim3 grid((K_TOT + GROUPS_PB - 1) / GROUPS_PB, B);
    SpeedPerturb_resample_kernel<<<grid, dim3(256), 0, stream>>>(in, out, args);
}